// Round 8
// baseline (111.628 us; speedup 1.0000x reference)
//
#include <hip/hip_runtime.h>

// out[c, y, w] = x[p, c, oy, ox]
//   iy = y / 126, jx = w / 126  (clamps never trigger for y,w < 1024)
//   oy = y - iy*126, ox = w - jx*126, p = iy*9 + jx
// x: (81, 64, 128, 128) f32; out: (64, 1024, 1024) f32. Pure injective gather,
// memory-bound, zero reuse.
//
// Round 8 = round 7 (nt, guard-free, 101.0 us) with QUAD-per-thread:
//  - each thread owns 4 consecutive outputs; the two PAIRS of a quad never
//    split a jx-segment (segment starts 126k are even), so 2x 8-B nt loads
//    + 1x 16-B nt store. Store instruction count halves; store shape matches
//    the 7 TB/s fill stream (1024 B dense per wave instruction).
//  - size_t oaddr[8] (16 VGPR) -> unsigned oidx[4] (4 VGPR): stay under the
//    64-VGPR occupancy cliff (m69).
//  - still 8 loads in flight per thread per sweep.

typedef float v2f __attribute__((ext_vector_type(2)));
typedef float v4f __attribute__((ext_vector_type(4)));

__global__ __launch_bounds__(256) void patch_gather_kernel(
    const float* __restrict__ x, float* __restrict__ out,
    unsigned n_sweeps, unsigned tail_start, unsigned n_quads) {
    const unsigned tid = threadIdx.x;
    const unsigned chunk = 256u * 4u;                       // quads per block-sweep
    const unsigned stride = gridDim.x * chunk;              // quads per grid-sweep
    unsigned base = blockIdx.x * chunk + tid;

    for (unsigned s = 0; s < n_sweeps; ++s, base += stride) {
        v4f pr[4];
        unsigned oidx[4];
        #pragma unroll
        for (int k = 0; k < 4; ++k) {
            const unsigned u = base + (unsigned)k * 256u;   // quad idx, lanes contiguous
            const unsigned idx = u << 2;                    // flat output index (mult of 4)
            const unsigned c  = idx >> 20;                  // H*W = 2^20
            const unsigned y  = (idx >> 10) & 1023u;
            const unsigned w0 = idx & 1023u;                // multiple of 4

            const unsigned iy = y / 126u;                   // magic-mul
            const unsigned oy = y - iy * 126u;
            const unsigned jxA = w0 / 126u;
            const unsigned oxA = w0 - jxA * 126u;           // even
            const unsigned w2  = w0 + 2u;
            const unsigned jxB = w2 / 126u;
            const unsigned oxB = w2 - jxB * 126u;           // even

            const size_t rowbase = ((size_t)(iy * 576u + c) << 14) + (oy << 7);
            const v2f a = __builtin_nontemporal_load(
                reinterpret_cast<const v2f*>(&x[rowbase + ((size_t)jxA << 20) + oxA]));
            const v2f b = __builtin_nontemporal_load(
                reinterpret_cast<const v2f*>(&x[rowbase + ((size_t)jxB << 20) + oxB]));
            v4f v; v.x = a.x; v.y = a.y; v.z = b.x; v.w = b.y;
            pr[k] = v;
            oidx[k] = idx;
        }
        #pragma unroll
        for (int k = 0; k < 4; ++k) {
            __builtin_nontemporal_store(
                pr[k], reinterpret_cast<v4f*>(&out[oidx[k]]));
        }
    }

    // Generic tail (empty for the real shape; kept for safety).
    for (unsigned u = tail_start + blockIdx.x * blockDim.x + tid; u < n_quads;
         u += gridDim.x * blockDim.x) {
        const unsigned idx = u << 2;
        const unsigned c  = idx >> 20;
        const unsigned y  = (idx >> 10) & 1023u;
        const unsigned w0 = idx & 1023u;
        const unsigned iy = y / 126u;
        const unsigned oy = y - iy * 126u;
        const unsigned jxA = w0 / 126u;
        const unsigned oxA = w0 - jxA * 126u;
        const unsigned w2  = w0 + 2u;
        const unsigned jxB = w2 / 126u;
        const unsigned oxB = w2 - jxB * 126u;
        const size_t rowbase = ((size_t)(iy * 576u + c) << 14) + (oy << 7);
        const v2f a = __builtin_nontemporal_load(
            reinterpret_cast<const v2f*>(&x[rowbase + ((size_t)jxA << 20) + oxA]));
        const v2f b = __builtin_nontemporal_load(
            reinterpret_cast<const v2f*>(&x[rowbase + ((size_t)jxB << 20) + oxB]));
        v4f v; v.x = a.x; v.y = a.y; v.z = b.x; v.w = b.y;
        __builtin_nontemporal_store(v, reinterpret_cast<v4f*>(&out[idx]));
    }
}

extern "C" void kernel_launch(void* const* d_in, const int* in_sizes, int n_in,
                              void* d_out, int out_size, void* d_ws, size_t ws_size,
                              hipStream_t stream) {
    const float* x = (const float*)d_in[0];
    float* out = (float*)d_out;

    const unsigned n_quads = (unsigned)(out_size / 4);      // 2^24
    const unsigned grid = 2048, block = 256, K = 4;
    const unsigned per_sweep = grid * block * K;            // 2^21
    const unsigned n_sweeps = n_quads / per_sweep;          // 8 (exact)
    const unsigned tail_start = n_sweeps * per_sweep;       // == n_quads

    patch_gather_kernel<<<grid, block, 0, stream>>>(x, out, n_sweeps, tail_start, n_quads);
}

// Round 9
// 100.399 us; speedup vs baseline: 1.1118x; 1.1118x over previous
//
#include <hip/hip_runtime.h>

// out[c, y, w] = x[p, c, oy, ox]
//   iy = y / 126, jx = w / 126  (clamps never trigger for y,w < 1024)
//   oy = y - iy*126, ox = w - jx*126, p = iy*9 + jx
// x: (81, 64, 128, 128) f32; out: (64, 1024, 1024) f32. Pure injective gather,
// memory-bound, zero reuse.
//
// Round 9 = round 7 (best: 101.0 us, nt both streams, guard-free, PAIR-granule
// 100%-dense loads+stores) minus the size_t oaddr[8] array: store addresses
// are out + 2*base + k*512, computed from one base pointer (saves ~16 VGPR +
// 64-bit addr VALU). Round 8's quad-granule regressed to 111.6 us because its
// load instructions were only 50% lane-dense; density is a real ~10% lever
// under nt (r2: 25% = 122, r7: 100% = 101).

typedef float v2f __attribute__((ext_vector_type(2)));

__global__ __launch_bounds__(256) void patch_gather_kernel(
    const float* __restrict__ x, float* __restrict__ out,
    unsigned n_sweeps, unsigned tail_start, unsigned n_pairs) {
    const unsigned tid = threadIdx.x;
    const unsigned chunk = 256u * 8u;                       // pairs per block-sweep
    const unsigned stride = gridDim.x * chunk;              // pairs per grid-sweep
    unsigned base = blockIdx.x * chunk + tid;

    for (unsigned s = 0; s < n_sweeps; ++s, base += stride) {
        v2f pr[8];
        #pragma unroll
        for (int k = 0; k < 8; ++k) {
            const unsigned q = base + (unsigned)k * 256u;   // pair idx, lanes contiguous
            const unsigned idx = q << 1;                    // flat output index (even)
            const unsigned c  = idx >> 20;                  // H*W = 2^20
            const unsigned y  = (idx >> 10) & 1023u;
            const unsigned w0 = idx & 1023u;                // even

            const unsigned iy = y / 126u;                   // magic-mul
            const unsigned oy = y - iy * 126u;
            const unsigned jx = w0 / 126u;                  // magic-mul
            const unsigned ox = w0 - jx * 126u;             // even

            const size_t addr = ((size_t)(iy * 576u + c) << 14)
                              + ((size_t)jx << 20) + (oy << 7) + ox;
            pr[k] = __builtin_nontemporal_load(
                reinterpret_cast<const v2f*>(&x[addr]));
        }
        float* obase = out + ((size_t)base << 1);           // one 64-bit base
        #pragma unroll
        for (int k = 0; k < 8; ++k) {
            __builtin_nontemporal_store(
                pr[k], reinterpret_cast<v2f*>(obase + (unsigned)k * 512u));
        }
    }

    // Generic tail (empty for the real shape; kept for safety).
    for (unsigned q = tail_start + blockIdx.x * blockDim.x + tid; q < n_pairs;
         q += gridDim.x * blockDim.x) {
        const unsigned idx = q << 1;
        const unsigned c  = idx >> 20;
        const unsigned y  = (idx >> 10) & 1023u;
        const unsigned w0 = idx & 1023u;
        const unsigned iy = y / 126u;
        const unsigned oy = y - iy * 126u;
        const unsigned jx = w0 / 126u;
        const unsigned ox = w0 - jx * 126u;
        const size_t addr = ((size_t)(iy * 576u + c) << 14)
                          + ((size_t)jx << 20) + (oy << 7) + ox;
        const v2f v = __builtin_nontemporal_load(
            reinterpret_cast<const v2f*>(&x[addr]));
        __builtin_nontemporal_store(v, reinterpret_cast<v2f*>(&out[idx]));
    }
}

extern "C" void kernel_launch(void* const* d_in, const int* in_sizes, int n_in,
                              void* d_out, int out_size, void* d_ws, size_t ws_size,
                              hipStream_t stream) {
    const float* x = (const float*)d_in[0];
    float* out = (float*)d_out;

    const unsigned n_pairs = (unsigned)(out_size / 2);      // 2^25
    const unsigned grid = 2048, block = 256, K = 8;
    const unsigned per_sweep = grid * block * K;            // 2^22
    const unsigned n_sweeps = n_pairs / per_sweep;          // 8 (exact)
    const unsigned tail_start = n_sweeps * per_sweep;       // == n_pairs

    patch_gather_kernel<<<grid, block, 0, stream>>>(x, out, n_sweeps, tail_start, n_pairs);
}